// Round 8
// baseline (41.078 us; speedup 1.0000x reference)
//
#include <hip/hip_runtime.h>

// Problem constants (match reference)
#define Bn 16
#define Kn 17
#define Hn 256
#define Wn 256
#define Mn 30
#define NFLAT (Kn * Hn * Wn)                   // 1,114,112 tags per image
#define TOTAL ((long long)Bn * Kn * Hn * Wn)   // 17,825,792 elements
#define NVEC  ((int)(TOTAL / 4))               // float4 count = 4,456,448
#define NPAIR (NVEC / 2)                       // float4-pair count = 2,228,224

#define HEAT_BLOCKS 2048
#define THREADS 256
#define AE_BLOCKS Bn
#define NBLOCKS (HEAT_BLOCKS + AE_BLOCKS)

typedef float f32x4 __attribute__((ext_vector_type(4)));

// ---------------------------------------------------------------------------
// Kernel 1: AE blocks [0,16) + heat MSE partial blocks [16, 16+2048).
// gt and mask are loaded non-temporally (no L2/L3 allocation); only pred
// (71 MB) allocates -> fully Infinity-Cache-resident across replays, and the
// HBM path streams gt+mask concurrently with L3 serving pred.
// ---------------------------------------------------------------------------
__global__ __launch_bounds__(THREADS) void fused_kernel(
    const f32x4* __restrict__ pred,
    const f32x4* __restrict__ gt,
    const f32x4* __restrict__ mask,
    const float* __restrict__ tags,      // [B, NFLAT]
    const int* __restrict__ joints,      // [B, M, K, 2]
    float* __restrict__ partial,         // [HEAT_BLOCKS]
    float* __restrict__ push_arr,        // [Bn]
    float* __restrict__ pull_arr) {      // [Bn]
    __shared__ float smem[64];

    if (blockIdx.x >= AE_BLOCKS) {
        // ---------------- heatmap MSE partial ----------------
        int hb = blockIdx.x - AE_BLOCKS;
        int tid = hb * THREADS + threadIdx.x;
        const int stride = HEAT_BLOCKS * THREADS;  // 524,288
        float acc0 = 0.f, acc1 = 0.f;
        for (int i = tid; i < NPAIR; i += stride) {
            f32x4 p0 = pred[2 * i], p1 = pred[2 * i + 1];
            f32x4 g0 = __builtin_nontemporal_load(gt + 2 * i);
            f32x4 g1 = __builtin_nontemporal_load(gt + 2 * i + 1);
            f32x4 m0 = __builtin_nontemporal_load(mask + 2 * i);
            f32x4 m1 = __builtin_nontemporal_load(mask + 2 * i + 1);
            f32x4 d0 = p0 - g0;
            f32x4 d1 = p1 - g1;
            f32x4 s0 = d0 * d0 * m0;
            f32x4 s1 = d1 * d1 * m1;
            acc0 += s0.x + s0.y + s0.z + s0.w;
            acc1 += s1.x + s1.y + s1.z + s1.w;
        }
        float a = acc0 + acc1;
        // intra-wave reduce (64 lanes)
        for (int off = 32; off > 0; off >>= 1) a += __shfl_down(a, off, 64);
        int wave = threadIdx.x >> 6;
        if ((threadIdx.x & 63) == 0) smem[wave] = a;
        __syncthreads();
        if (threadIdx.x == 0)
            partial[hb] = smem[0] + smem[1] + smem[2] + smem[3];
    } else {
        // ---------------- AE (push/pull) loss, one image per block ----------
        int b = blockIdx.x;
        int lane = threadIdx.x;  // only wave 0 (lanes 0..63) participates

        float mu = 0.f, pullpp = 0.f, validf = 0.f;
        if (lane < Mn) {
            const int* jb = joints + ((long long)(b * Mn + lane) * Kn) * 2;
            const float* tb = tags + (long long)b * NFLAT;
            float t[Kn], v[Kn];
            float cnt = 0.f, st = 0.f;
#pragma unroll
            for (int k = 0; k < Kn; k++) {
                int id = jb[2 * k];
                int vi = jb[2 * k + 1];
                float tv = tb[id];
                t[k] = tv;
                v[k] = (vi > 0) ? 1.f : 0.f;
                cnt += v[k];
                st += v[k] * tv;
            }
            float sc = fmaxf(cnt, 1.f);
            mu = st / sc;
            float pp = 0.f;
#pragma unroll
            for (int k = 0; k < Kn; k++) {
                float d = t[k] - mu;
                pp += v[k] * d * d;
            }
            pullpp = pp / sc;
            validf = (cnt > 0.f) ? 1.f : 0.f;
            smem[lane] = mu;          // mu in smem[0..29]
            smem[32 + lane] = validf; // valid in smem[32..61]
        }
        __syncthreads();

        if (lane < 64) {
            float nv = validf;
            float pv = (validf > 0.f) ? pullpp : 0.f;
            float sm = 0.f;
            if (lane < Mn && validf > 0.f) {
                for (int j = 0; j < Mn; j++) {
                    if (smem[32 + j] > 0.f) {
                        float d = mu - smem[j];
                        sm += expf(-(d * d));
                    }
                }
            }
            for (int off = 32; off > 0; off >>= 1) {
                nv += __shfl_down(nv, off, 64);
                pv += __shfl_down(pv, off, 64);
                sm += __shfl_down(sm, off, 64);
            }
            if (lane == 0) {
                float n = nv;
                float pull = pv / fmaxf(n, 1.f);
                float denom = fmaxf((n - 1.f) * n, 1.f);
                float push = (n >= 2.f) ? (sm - n) / denom * 0.5f : 0.f;
                push_arr[b] = push;
                pull_arr[b] = pull;
            }
        }
    }
}

// ---------------------------------------------------------------------------
// Kernel 2: finalize — reduce partials (double) + average push/pull
// ---------------------------------------------------------------------------
__global__ __launch_bounds__(256) void finalize_kernel(
    const float* __restrict__ partial,
    const float* __restrict__ push_arr,
    const float* __restrict__ pull_arr,
    float* __restrict__ out) {
    __shared__ double sd[256];
    double acc = 0.0;
    for (int i = threadIdx.x; i < HEAT_BLOCKS; i += 256) acc += (double)partial[i];
    sd[threadIdx.x] = acc;
    __syncthreads();
    for (int off = 128; off > 0; off >>= 1) {
        if (threadIdx.x < off) sd[threadIdx.x] += sd[threadIdx.x + off];
        __syncthreads();
    }
    if (threadIdx.x == 0) {
        double heat = sd[0] / (double)TOTAL;       // HEATMAPS_LOSS_FACTOR = 1.0
        float psum = 0.f, lsum = 0.f;
        for (int b = 0; b < Bn; b++) {
            psum += push_arr[b];
            lsum += pull_arr[b];
        }
        out[0] = (float)heat;
        out[1] = (psum / (float)Bn) * 0.001f;      // PUSH_LOSS_FACTOR
        out[2] = (lsum / (float)Bn) * 0.001f;      // PULL_LOSS_FACTOR
    }
}

// ---------------------------------------------------------------------------
extern "C" void kernel_launch(void* const* d_in, const int* in_sizes, int n_in,
                              void* d_out, int out_size, void* d_ws, size_t ws_size,
                              hipStream_t stream) {
    const float* heatmaps_pred = (const float*)d_in[0];
    const float* heatmaps      = (const float*)d_in[1];
    const float* masks         = (const float*)d_in[2];
    const float* tags_pred     = (const float*)d_in[3];
    const int*   joints        = (const int*)d_in[4];
    float* out = (float*)d_out;

    float* ws = (float*)d_ws;
    float* partial  = ws;                 // [HEAT_BLOCKS]
    float* push_arr = ws + HEAT_BLOCKS;   // [Bn]
    float* pull_arr = push_arr + Bn;      // [Bn]

    fused_kernel<<<NBLOCKS, THREADS, 0, stream>>>(
        (const f32x4*)heatmaps_pred, (const f32x4*)heatmaps,
        (const f32x4*)masks, tags_pred, joints, partial, push_arr, pull_arr);

    finalize_kernel<<<1, 256, 0, stream>>>(partial, push_arr, pull_arr, out);
}

// Round 9
// 39.239 us; speedup vs baseline: 1.0469x; 1.0469x over previous
//
#include <hip/hip_runtime.h>

// Problem constants (match reference)
#define Bn 16
#define Kn 17
#define Hn 256
#define Wn 256
#define Mn 30
#define NFLAT (Kn * Hn * Wn)                   // 1,114,112 tags per image
#define TOTAL ((long long)Bn * Kn * Hn * Wn)   // 17,825,792 elements
#define NVEC  ((int)(TOTAL / 4))               // float4 count = 4,456,448
#define NPAIR (NVEC / 2)                       // float4-pair count = 2,228,224

#define HEAT_BLOCKS 2048
#define THREADS 256
#define AE_BLOCKS Bn
#define NBLOCKS (HEAT_BLOCKS + AE_BLOCKS)

typedef float f32x4 __attribute__((ext_vector_type(4)));

// ---------------------------------------------------------------------------
// Kernel 1: AE blocks [0,16) + heat MSE partial blocks [16, 16+2048).
// mask is loaded non-temporally: keeps mask from evicting pred/gt in the
// per-XCD L2s (R7-measured best: 39.9 us clean; R8 showed nt on gt too
// regresses clean runs).
// ---------------------------------------------------------------------------
__global__ __launch_bounds__(THREADS) void fused_kernel(
    const f32x4* __restrict__ pred,
    const f32x4* __restrict__ gt,
    const f32x4* __restrict__ mask,
    const float* __restrict__ tags,      // [B, NFLAT]
    const int* __restrict__ joints,      // [B, M, K, 2]
    float* __restrict__ partial,         // [HEAT_BLOCKS]
    float* __restrict__ push_arr,        // [Bn]
    float* __restrict__ pull_arr) {      // [Bn]
    __shared__ float smem[64];

    if (blockIdx.x >= AE_BLOCKS) {
        // ---------------- heatmap MSE partial ----------------
        int hb = blockIdx.x - AE_BLOCKS;
        int tid = hb * THREADS + threadIdx.x;
        const int stride = HEAT_BLOCKS * THREADS;  // 524,288
        float acc0 = 0.f, acc1 = 0.f;
        for (int i = tid; i < NPAIR; i += stride) {
            f32x4 p0 = pred[2 * i], p1 = pred[2 * i + 1];
            f32x4 g0 = gt[2 * i],   g1 = gt[2 * i + 1];
            f32x4 m0 = __builtin_nontemporal_load(mask + 2 * i);
            f32x4 m1 = __builtin_nontemporal_load(mask + 2 * i + 1);
            f32x4 d0 = p0 - g0;
            f32x4 d1 = p1 - g1;
            f32x4 s0 = d0 * d0 * m0;
            f32x4 s1 = d1 * d1 * m1;
            acc0 += s0.x + s0.y + s0.z + s0.w;
            acc1 += s1.x + s1.y + s1.z + s1.w;
        }
        float a = acc0 + acc1;
        // intra-wave reduce (64 lanes)
        for (int off = 32; off > 0; off >>= 1) a += __shfl_down(a, off, 64);
        int wave = threadIdx.x >> 6;
        if ((threadIdx.x & 63) == 0) smem[wave] = a;
        __syncthreads();
        if (threadIdx.x == 0)
            partial[hb] = smem[0] + smem[1] + smem[2] + smem[3];
    } else {
        // ---------------- AE (push/pull) loss, one image per block ----------
        int b = blockIdx.x;
        int lane = threadIdx.x;  // only wave 0 (lanes 0..63) participates

        float mu = 0.f, pullpp = 0.f, validf = 0.f;
        if (lane < Mn) {
            const int* jb = joints + ((long long)(b * Mn + lane) * Kn) * 2;
            const float* tb = tags + (long long)b * NFLAT;
            float t[Kn], v[Kn];
            float cnt = 0.f, st = 0.f;
#pragma unroll
            for (int k = 0; k < Kn; k++) {
                int id = jb[2 * k];
                int vi = jb[2 * k + 1];
                float tv = tb[id];
                t[k] = tv;
                v[k] = (vi > 0) ? 1.f : 0.f;
                cnt += v[k];
                st += v[k] * tv;
            }
            float sc = fmaxf(cnt, 1.f);
            mu = st / sc;
            float pp = 0.f;
#pragma unroll
            for (int k = 0; k < Kn; k++) {
                float d = t[k] - mu;
                pp += v[k] * d * d;
            }
            pullpp = pp / sc;
            validf = (cnt > 0.f) ? 1.f : 0.f;
            smem[lane] = mu;          // mu in smem[0..29]
            smem[32 + lane] = validf; // valid in smem[32..61]
        }
        __syncthreads();

        if (lane < 64) {
            float nv = validf;
            float pv = (validf > 0.f) ? pullpp : 0.f;
            float sm = 0.f;
            if (lane < Mn && validf > 0.f) {
                for (int j = 0; j < Mn; j++) {
                    if (smem[32 + j] > 0.f) {
                        float d = mu - smem[j];
                        sm += expf(-(d * d));
                    }
                }
            }
            for (int off = 32; off > 0; off >>= 1) {
                nv += __shfl_down(nv, off, 64);
                pv += __shfl_down(pv, off, 64);
                sm += __shfl_down(sm, off, 64);
            }
            if (lane == 0) {
                float n = nv;
                float pull = pv / fmaxf(n, 1.f);
                float denom = fmaxf((n - 1.f) * n, 1.f);
                float push = (n >= 2.f) ? (sm - n) / denom * 0.5f : 0.f;
                push_arr[b] = push;
                pull_arr[b] = pull;
            }
        }
    }
}

// ---------------------------------------------------------------------------
// Kernel 2: finalize — reduce partials (double) + average push/pull
// ---------------------------------------------------------------------------
__global__ __launch_bounds__(256) void finalize_kernel(
    const float* __restrict__ partial,
    const float* __restrict__ push_arr,
    const float* __restrict__ pull_arr,
    float* __restrict__ out) {
    __shared__ double sd[256];
    double acc = 0.0;
    for (int i = threadIdx.x; i < HEAT_BLOCKS; i += 256) acc += (double)partial[i];
    sd[threadIdx.x] = acc;
    __syncthreads();
    for (int off = 128; off > 0; off >>= 1) {
        if (threadIdx.x < off) sd[threadIdx.x] += sd[threadIdx.x + off];
        __syncthreads();
    }
    if (threadIdx.x == 0) {
        double heat = sd[0] / (double)TOTAL;       // HEATMAPS_LOSS_FACTOR = 1.0
        float psum = 0.f, lsum = 0.f;
        for (int b = 0; b < Bn; b++) {
            psum += push_arr[b];
            lsum += pull_arr[b];
        }
        out[0] = (float)heat;
        out[1] = (psum / (float)Bn) * 0.001f;      // PUSH_LOSS_FACTOR
        out[2] = (lsum / (float)Bn) * 0.001f;      // PULL_LOSS_FACTOR
    }
}

// ---------------------------------------------------------------------------
extern "C" void kernel_launch(void* const* d_in, const int* in_sizes, int n_in,
                              void* d_out, int out_size, void* d_ws, size_t ws_size,
                              hipStream_t stream) {
    const float* heatmaps_pred = (const float*)d_in[0];
    const float* heatmaps      = (const float*)d_in[1];
    const float* masks         = (const float*)d_in[2];
    const float* tags_pred     = (const float*)d_in[3];
    const int*   joints        = (const int*)d_in[4];
    float* out = (float*)d_out;

    float* ws = (float*)d_ws;
    float* partial  = ws;                 // [HEAT_BLOCKS]
    float* push_arr = ws + HEAT_BLOCKS;   // [Bn]
    float* pull_arr = push_arr + Bn;      // [Bn]

    fused_kernel<<<NBLOCKS, THREADS, 0, stream>>>(
        (const f32x4*)heatmaps_pred, (const f32x4*)heatmaps,
        (const f32x4*)masks, tags_pred, joints, partial, push_arr, pull_arr);

    finalize_kernel<<<1, 256, 0, stream>>>(partial, push_arr, pull_arr, out);
}